// Round 10
// baseline (10314.121 us; speedup 1.0000x reference)
//
#include <hip/hip_runtime.h>

#define IMW 64
#define HW 4096
#define BATCH 64
#define NPIX (BATCH * HW)   // 262144
#define TPB 512             // threads per spatial block
#define PIXBLK 8            // pixel-blocks per image (4096/512)

// ---------------- bf16 helpers (manual, RNE) ----------------
__device__ inline float bfbits(unsigned int hi16) {
    union { unsigned int i; float f; } v; v.i = hi16; return v.f;
}
__device__ inline float bf_lo(unsigned int u) { return bfbits(u << 16); }
__device__ inline float bf_hi(unsigned int u) { return bfbits(u & 0xffff0000u); }
__device__ inline unsigned short f2bf(float f) {
    union { float f; unsigned int i; } v; v.f = f;
    unsigned int i = v.i;
    i += 0x7fff + ((i >> 16) & 1);
    return (unsigned short)(i >> 16);
}

// ---------------- fp16 pair helpers ----------------
__device__ inline unsigned pack_h2(float a, float b) {
    union { unsigned u; _Float16 h[2]; } v;
    v.h[0] = (_Float16)a;
    v.h[1] = (_Float16)b;
    return v.u;
}
__device__ inline float h_lo(unsigned u) {
    union { unsigned u; _Float16 h[2]; } v; v.u = u; return (float)v.h[0];
}
__device__ inline float h_hi(unsigned u) {
    union { unsigned u; _Float16 h[2]; } v; v.u = u; return (float)v.h[1];
}

// ---------------------------------------------------------------------------
// XCD-pinned swizzle (verified R3: FETCH 2.4GB -> 455MB). XCD = lin & 7 owns
// images [8*xcd, 8*xcd+8); all pixel/co blocks of an image on one XCD.
// ---------------------------------------------------------------------------
template <int CO_BLOCKS>
__device__ inline void swz(int lin, int& img, int& xblk, int& cob) {
    const int per_img = PIXBLK * CO_BLOCKS;
    int xcd = lin & 7;
    int s = lin >> 3;
    img = xcd * 8 + s / per_img;
    int r = s % per_img;
    cob = r / PIXBLK;
    xblk = r % PIXBLK;
}

// ---------------------------------------------------------------------------
// Direct 3x3 conv, pad=1. NHWC activations (stage-1 input NCHW fp32).
// IN_BF16: bf16 NHWC input. OUT_MODE: 0 = fp32 NHWC, 1 = bf16 NHWC packed,
// 2 = fp16 dword-planes [tap][pixel] (for offsets, COUT=18 -> 9 planes).
// ---------------------------------------------------------------------------
template <int CIN, int COUT, bool RELU, bool BIAS, bool AFF, bool IN_NCHW,
          bool IN_BF16, int OUT_MODE>
__global__ void conv3x3_k(const void* __restrict__ in_,
                          const float* __restrict__ w,
                          const float* __restrict__ bias,
                          const float* __restrict__ iscale,
                          const float* __restrict__ ishift,
                          void* __restrict__ out_) {
    __shared__ float lw[9 * CIN * COUT];
    __shared__ float lb[COUT];
    __shared__ float lsc[CIN];
    __shared__ float lsh[CIN];

    for (int dst = threadIdx.x; dst < 9 * CIN * COUT; dst += blockDim.x) {
        int co = dst % COUT;
        int kci = dst / COUT;
        int k = kci / CIN;
        int ci = kci % CIN;
        lw[dst] = w[(size_t)co * (CIN * 9) + ci * 9 + k];
    }
    if (threadIdx.x < COUT) lb[threadIdx.x] = BIAS ? bias[threadIdx.x] : 0.f;
    if (AFF && threadIdx.x < CIN) {
        lsc[threadIdx.x] = iscale[threadIdx.x];
        lsh[threadIdx.x] = ishift[threadIdx.x];
    }
    __syncthreads();

    int img, xblk, cob;
    swz<1>(blockIdx.x, img, xblk, cob);
    int b = img;
    int pos = xblk * TPB + threadIdx.x;
    int p = (b << 12) + pos;
    int y = pos >> 6;
    int x = pos & 63;

    float acc[COUT];
#pragma unroll
    for (int co = 0; co < COUT; ++co) acc[co] = lb[co];

#pragma unroll 1
    for (int k = 0; k < 9; ++k) {
        int ky = k / 3, kx = k - ky * 3;
        int yy = y + ky - 1, xx = x + kx - 1;
        if (yy < 0 || yy >= IMW || xx < 0 || xx >= IMW) continue;

        float vin[CIN];
        if constexpr (IN_NCHW) {
            const float* ip = (const float*)in_;
#pragma unroll
            for (int ci = 0; ci < CIN; ++ci)
                vin[ci] = ip[((size_t)(b * CIN + ci) << 12) + yy * IMW + xx];
        } else if constexpr (!IN_BF16) {
            const float* ip = (const float*)in_ + ((size_t)((b << 12) + yy * IMW + xx)) * CIN;
#pragma unroll
            for (int c4 = 0; c4 < CIN / 4; ++c4) {
                float4 v = *(const float4*)(ip + c4 * 4);
                vin[c4 * 4 + 0] = v.x;
                vin[c4 * 4 + 1] = v.y;
                vin[c4 * 4 + 2] = v.z;
                vin[c4 * 4 + 3] = v.w;
            }
        } else if constexpr (CIN % 8 == 0) {
            const uint4* ip = (const uint4*)((const unsigned short*)in_ +
                                             ((size_t)((b << 12) + yy * IMW + xx)) * CIN);
#pragma unroll
            for (int c8 = 0; c8 < CIN / 8; ++c8) {
                uint4 u = ip[c8];
                vin[c8 * 8 + 0] = bf_lo(u.x); vin[c8 * 8 + 1] = bf_hi(u.x);
                vin[c8 * 8 + 2] = bf_lo(u.y); vin[c8 * 8 + 3] = bf_hi(u.y);
                vin[c8 * 8 + 4] = bf_lo(u.z); vin[c8 * 8 + 5] = bf_hi(u.z);
                vin[c8 * 8 + 6] = bf_lo(u.w); vin[c8 * 8 + 7] = bf_hi(u.w);
            }
        } else {
            const uint2* ip = (const uint2*)((const unsigned short*)in_ +
                                             ((size_t)((b << 12) + yy * IMW + xx)) * CIN);
#pragma unroll
            for (int c4 = 0; c4 < CIN / 4; ++c4) {
                uint2 u = ip[c4];
                vin[c4 * 4 + 0] = bf_lo(u.x); vin[c4 * 4 + 1] = bf_hi(u.x);
                vin[c4 * 4 + 2] = bf_lo(u.y); vin[c4 * 4 + 3] = bf_hi(u.y);
            }
        }
        if constexpr (AFF) {
#pragma unroll
            for (int ci = 0; ci < CIN; ++ci)
                vin[ci] = fmaf(vin[ci], lsc[ci], lsh[ci]);
        }
#pragma unroll
        for (int ci = 0; ci < CIN; ++ci) {
            float s = vin[ci];
            const float* wr = &lw[(k * CIN + ci) * COUT];
#pragma unroll
            for (int co = 0; co < COUT; ++co)
                acc[co] = fmaf(wr[co], s, acc[co]);
        }
    }

    if (RELU) {
#pragma unroll
        for (int co = 0; co < COUT; ++co) acc[co] = fmaxf(acc[co], 0.f);
    }

    if constexpr (OUT_MODE == 2) {
        unsigned* o = (unsigned*)out_;
#pragma unroll
        for (int i = 0; i < COUT / 2; ++i)
            o[(size_t)i * NPIX + p] = pack_h2(acc[2 * i], acc[2 * i + 1]);
    } else if constexpr (OUT_MODE == 1) {
        unsigned int us[COUT / 2];
#pragma unroll
        for (int i = 0; i < COUT / 2; ++i)
            us[i] = (unsigned int)f2bf(acc[2 * i]) | ((unsigned int)f2bf(acc[2 * i + 1]) << 16);
        uint2* o2 = (uint2*)((unsigned short*)out_ + (size_t)p * COUT);
#pragma unroll
        for (int i = 0; i < COUT / 4; ++i)
            o2[i] = make_uint2(us[2 * i], us[2 * i + 1]);
    } else {
        float* op = (float*)out_ + (size_t)p * COUT;
        if constexpr (COUT % 4 == 0) {
#pragma unroll
            for (int c4 = 0; c4 < COUT / 4; ++c4)
                *(float4*)(op + c4 * 4) =
                    make_float4(acc[c4 * 4], acc[c4 * 4 + 1], acc[c4 * 4 + 2], acc[c4 * 4 + 3]);
        } else {
#pragma unroll
            for (int c2 = 0; c2 < COUT / 2; ++c2)
                *(float2*)(op + c2 * 2) = make_float2(acc[c2 * 2], acc[c2 * 2 + 1]);
        }
    }
}

// ---------------------------------------------------------------------------
// deform1 kernel (R7-proven config, no launch_bounds): per-thread bilinear,
// bf16 NHWC in, fp16 plane offsets, full 9-tap LDS weights.
// ---------------------------------------------------------------------------
template <int CIN, int COUT_TOT, int COUT_BLK, int CO_BLOCKS>
__global__ void deform_k(const void* __restrict__ in_,
                         const unsigned* __restrict__ off,
                         const float* __restrict__ w,
                         const float* __restrict__ iscale,
                         const float* __restrict__ ishift,
                         void* __restrict__ out_) {
    __shared__ float lw[9 * CIN * COUT_BLK];
    __shared__ float lsc[CIN];
    __shared__ float lsh[CIN];

    int img, xblk, cob;
    swz<CO_BLOCKS>(blockIdx.x, img, xblk, cob);
    int co_base = cob * COUT_BLK;

    for (int dst = threadIdx.x; dst < 9 * CIN * COUT_BLK; dst += blockDim.x) {
        int co = dst % COUT_BLK;
        int kci = dst / COUT_BLK;
        int k = kci / CIN;
        int ci = kci % CIN;
        lw[dst] = w[(size_t)(co_base + co) * (CIN * 9) + ci * 9 + k];
    }
    if (threadIdx.x < CIN) {
        lsc[threadIdx.x] = iscale[threadIdx.x];
        lsh[threadIdx.x] = ishift[threadIdx.x];
    }
    __syncthreads();

    int b = img;
    int pos = xblk * TPB + threadIdx.x;
    int p = (b << 12) + pos;
    int y = pos >> 6;
    int x = pos & 63;

    float acc[COUT_BLK];
#pragma unroll
    for (int co = 0; co < COUT_BLK; ++co) acc[co] = 0.f;

    unsigned od[9];
#pragma unroll
    for (int j = 0; j < 9; ++j) od[j] = off[(size_t)j * NPIX + p];

    const unsigned short* ib = (const unsigned short*)in_ + (size_t)b * HW * CIN;

#pragma unroll 1
    for (int k = 0; k < 9; ++k) {
        int ky = k / 3, kx = k - ky * 3;
        float py = (float)(y + ky - 1) + h_lo(od[k]);
        float px = (float)(x + kx - 1) + h_hi(od[k]);
        float fy = floorf(py), fx = floorf(px);
        float wy = py - fy, wx = px - fx;
        int y0 = (int)fy, x0 = (int)fx;
        int y1 = y0 + 1, x1 = x0 + 1;
        bool vy0 = (unsigned)y0 < (unsigned)IMW;
        bool vy1 = (unsigned)y1 < (unsigned)IMW;
        bool vx0 = (unsigned)x0 < (unsigned)IMW;
        bool vx1 = (unsigned)x1 < (unsigned)IMW;
        int cy0 = min(max(y0, 0), IMW - 1), cy1 = min(max(y1, 0), IMW - 1);
        int cx0 = min(max(x0, 0), IMW - 1), cx1 = min(max(x1, 0), IMW - 1);
        float w00 = (1.f - wy) * (1.f - wx) * ((vy0 & vx0) ? 1.f : 0.f);
        float w01 = (1.f - wy) * wx * ((vy0 & vx1) ? 1.f : 0.f);
        float w10 = wy * (1.f - wx) * ((vy1 & vx0) ? 1.f : 0.f);
        float w11 = wy * wx * ((vy1 & vx1) ? 1.f : 0.f);
        float wsum = w00 + w01 + w10 + w11;

        const uint2* q00 = (const uint2*)(ib + (size_t)(cy0 * IMW + cx0) * CIN);
        const uint2* q01 = (const uint2*)(ib + (size_t)(cy0 * IMW + cx1) * CIN);
        const uint2* q10 = (const uint2*)(ib + (size_t)(cy1 * IMW + cx0) * CIN);
        const uint2* q11 = (const uint2*)(ib + (size_t)(cy1 * IMW + cx1) * CIN);
#pragma unroll
        for (int c4 = 0; c4 < CIN / 4; ++c4) {
            uint2 a = q00[c4], bq = q01[c4], c = q10[c4], d = q11[c4];
#pragma unroll
            for (int h = 0; h < 2; ++h) {
                unsigned int ua = (&a.x)[h], ub = (&bq.x)[h];
                unsigned int uc = (&c.x)[h], ud = (&d.x)[h];
                int ci0 = c4 * 4 + h * 2;
                float r0 = w00 * bf_lo(ua) + w01 * bf_lo(ub) +
                           w10 * bf_lo(uc) + w11 * bf_lo(ud);
                float r1 = w00 * bf_hi(ua) + w01 * bf_hi(ub) +
                           w10 * bf_hi(uc) + w11 * bf_hi(ud);
                float s0 = fmaf(r0, lsc[ci0], lsh[ci0] * wsum);
                float s1 = fmaf(r1, lsc[ci0 + 1], lsh[ci0 + 1] * wsum);
                const float* wr0 = &lw[(k * CIN + ci0) * COUT_BLK];
                const float* wr1 = &lw[(k * CIN + ci0 + 1) * COUT_BLK];
#pragma unroll
                for (int co = 0; co < COUT_BLK; ++co)
                    acc[co] = fmaf(wr0[co], s0, acc[co]);
#pragma unroll
                for (int co = 0; co < COUT_BLK; ++co)
                    acc[co] = fmaf(wr1[co], s1, acc[co]);
            }
        }
    }

#pragma unroll
    for (int co = 0; co < COUT_BLK; ++co) acc[co] = fmaxf(acc[co], 0.f);

    unsigned int us[COUT_BLK / 2];
#pragma unroll
    for (int i = 0; i < COUT_BLK / 2; ++i)
        us[i] = (unsigned int)f2bf(acc[2 * i]) | ((unsigned int)f2bf(acc[2 * i + 1]) << 16);
    unsigned short* ob = (unsigned short*)out_ + (size_t)p * COUT_TOT + co_base;
    uint2* o2 = (uint2*)ob;
#pragma unroll
    for (int i = 0; i < COUT_BLK / 4; ++i)
        o2[i] = make_uint2(us[2 * i], us[2 * i + 1]);
}

// ---------------------------------------------------------------------------
// R10: deform2 sample-once via LDS sharing. Block = 512 thr = 128 pix × 4
// co-groups. Per tap: gather+bilinear each pixel ONCE into bf16 LDS samples
// (stride 21 dwords, coprime 32 -> conflict-free); FMA phase: thread owns
// acc[16] (no VGPR cliff), weights per-tap double-buffered, wave-uniform
// float4 broadcast reads. One barrier/tap; next-tap loads issued before FMA.
// ---------------------------------------------------------------------------
__device__ inline void bil8(uint4 c00, uint4 c01, uint4 c10, uint4 c11,
                            float w00, float w01, float w10, float w11, float wsum,
                            const float* lsc, const float* lsh, int ci0,
                            unsigned out[4]) {
#pragma unroll
    for (int h = 0; h < 4; ++h) {
        unsigned ua = (&c00.x)[h], ub = (&c01.x)[h];
        unsigned uc = (&c10.x)[h], ud = (&c11.x)[h];
        float r0 = w00 * bf_lo(ua) + w01 * bf_lo(ub) + w10 * bf_lo(uc) + w11 * bf_lo(ud);
        float r1 = w00 * bf_hi(ua) + w01 * bf_hi(ub) + w10 * bf_hi(uc) + w11 * bf_hi(ud);
        int ci = ci0 + 2 * h;
        float s0 = fmaf(r0, lsc[ci], lsh[ci] * wsum);
        float s1 = fmaf(r1, lsc[ci + 1], lsh[ci + 1] * wsum);
        out[h] = (unsigned)f2bf(s0) | ((unsigned)f2bf(s1) << 16);
    }
}

__global__ void deform2_smp_k(const unsigned short* __restrict__ in_,  // h3 bf16 NHWC
                              const unsigned* __restrict__ off,        // fp16 planes
                              const float* __restrict__ wgt,           // wd2 [64][360]
                              const float* __restrict__ iscale,
                              const float* __restrict__ ishift,
                              float* __restrict__ em) {
    constexpr int CIN = 40, PPB = 128, SSTR = 21;
    __shared__ unsigned smp[2][PPB * SSTR];     // 21504 B
    __shared__ float lw[2][CIN * 64];           // 20480 B
    __shared__ float lsc[CIN], lsh[CIN];

    int lin = blockIdx.x;
    int xcd = lin & 7, sb = lin >> 3;
    int img = xcd * 8 + (sb >> 5);              // 32 xblks/image
    int xblk = sb & 31;

    int t = threadIdx.x;
    if (t < CIN) { lsc[t] = iscale[t]; lsh[t] = ishift[t]; }
    __syncthreads();

    int pix = t & (PPB - 1);
    int cog = t >> 7;                           // 0..3
    int lpos = xblk * PPB + pix;
    int pg = (img << 12) + lpos;
    int y = lpos >> 6, x = lpos & 63;
    const unsigned short* ib = in_ + (size_t)img * HW * CIN;
    bool dual = (t < PPB);                      // waves 0,1 also do chunk 4
    int ciA = cog * 8;

    auto tapgeo = [&](int k, const unsigned short*& p00, const unsigned short*& p01,
                      const unsigned short*& p10, const unsigned short*& p11,
                      float& w00, float& w01, float& w10, float& w11, float& wsum) {
        unsigned odv = off[(size_t)k * NPIX + pg];
        int ky = k / 3, kx = k - ky * 3;
        float py = (float)(y + ky - 1) + h_lo(odv);
        float px = (float)(x + kx - 1) + h_hi(odv);
        float fy = floorf(py), fx = floorf(px);
        float wy = py - fy, wx = px - fx;
        int y0 = (int)fy, x0 = (int)fx, y1 = y0 + 1, x1 = x0 + 1;
        bool vy0 = (unsigned)y0 < 64u, vy1 = (unsigned)y1 < 64u;
        bool vx0 = (unsigned)x0 < 64u, vx1 = (unsigned)x1 < 64u;
        int cy0 = min(max(y0, 0), 63), cy1 = min(max(y1, 0), 63);
        int cx0 = min(max(x0, 0), 63), cx1 = min(max(x1, 0), 63);
        w00 = (1.f - wy) * (1.f - wx) * ((vy0 & vx0) ? 1.f : 0.f);
        w01 = (1.f - wy) * wx * ((vy0 & vx1) ? 1.f : 0.f);
        w10 = wy * (1.f - wx) * ((vy1 & vx0) ? 1.f : 0.f);
        w11 = wy * wx * ((vy1 & vx1) ? 1.f : 0.f);
        wsum = w00 + w01 + w10 + w11;
        p00 = ib + (size_t)(cy0 * 64 + cx0) * CIN;
        p01 = ib + (size_t)(cy0 * 64 + cx1) * CIN;
        p10 = ib + (size_t)(cy1 * 64 + cx0) * CIN;
        p11 = ib + (size_t)(cy1 * 64 + cx1) * CIN;
    };

    // prologue: tap 0 samples + weights
    {
        const unsigned short *p00, *p01, *p10, *p11;
        float w00, w01, w10, w11, wsum;
        tapgeo(0, p00, p01, p10, p11, w00, w01, w10, w11, wsum);
        uint4 a = *(const uint4*)(p00 + ciA), b = *(const uint4*)(p01 + ciA);
        uint4 c = *(const uint4*)(p10 + ciA), d = *(const uint4*)(p11 + ciA);
        unsigned o[4];
        bil8(a, b, c, d, w00, w01, w10, w11, wsum, lsc, lsh, ciA, o);
        unsigned* dst = &smp[0][pix * SSTR + cog * 4];
        dst[0] = o[0]; dst[1] = o[1]; dst[2] = o[2]; dst[3] = o[3];
        if (dual) {
            uint4 a2 = *(const uint4*)(p00 + 32), b2 = *(const uint4*)(p01 + 32);
            uint4 c2 = *(const uint4*)(p10 + 32), d2 = *(const uint4*)(p11 + 32);
            unsigned o2[4];
            bil8(a2, b2, c2, d2, w00, w01, w10, w11, wsum, lsc, lsh, 32, o2);
            unsigned* dd = &smp[0][pix * SSTR + 16];
            dd[0] = o2[0]; dd[1] = o2[1]; dd[2] = o2[2]; dd[3] = o2[3];
        }
#pragma unroll
        for (int r = 0; r < 5; ++r) {
            int dd = r * 512 + t;
            lw[0][dd] = wgt[(size_t)(dd & 63) * 360 + (dd >> 6) * 9 + 0];
        }
    }
    __syncthreads();

    float acc[16];
#pragma unroll
    for (int j = 0; j < 16; ++j) acc[j] = 0.f;

#pragma unroll 1
    for (int k = 0; k < 9; ++k) {
        int cb = k & 1, nb = cb ^ 1;
        uint4 a, b, c, d, a2, b2, c2, d2;
        float w00, w01, w10, w11, wsum;
        float wld[5];
        if (k < 8) {
            const unsigned short *p00, *p01, *p10, *p11;
            tapgeo(k + 1, p00, p01, p10, p11, w00, w01, w10, w11, wsum);
            a = *(const uint4*)(p00 + ciA); b = *(const uint4*)(p01 + ciA);
            c = *(const uint4*)(p10 + ciA); d = *(const uint4*)(p11 + ciA);
            if (dual) {
                a2 = *(const uint4*)(p00 + 32); b2 = *(const uint4*)(p01 + 32);
                c2 = *(const uint4*)(p10 + 32); d2 = *(const uint4*)(p11 + 32);
            }
#pragma unroll
            for (int r = 0; r < 5; ++r) {
                int dd = r * 512 + t;
                wld[r] = wgt[(size_t)(dd & 63) * 360 + (dd >> 6) * 9 + (k + 1)];
            }
        }

        // ---- FMA(k): samples per-lane, weights wave-uniform float4 ----
        const unsigned* sp = &smp[cb][pix * SSTR];
        const float* wb = &lw[cb][cog * 16];
#pragma unroll
        for (int cp = 0; cp < 20; ++cp) {
            unsigned u = sp[cp];
            float f0 = bf_lo(u), f1 = bf_hi(u);
            const float4* w0 = (const float4*)(wb + (2 * cp) * 64);
            const float4* w1 = (const float4*)(wb + (2 * cp + 1) * 64);
#pragma unroll
            for (int q = 0; q < 4; ++q) {
                float4 v0 = w0[q];
                acc[q * 4 + 0] = fmaf(v0.x, f0, acc[q * 4 + 0]);
                acc[q * 4 + 1] = fmaf(v0.y, f0, acc[q * 4 + 1]);
                acc[q * 4 + 2] = fmaf(v0.z, f0, acc[q * 4 + 2]);
                acc[q * 4 + 3] = fmaf(v0.w, f0, acc[q * 4 + 3]);
            }
#pragma unroll
            for (int q = 0; q < 4; ++q) {
                float4 v1 = w1[q];
                acc[q * 4 + 0] = fmaf(v1.x, f1, acc[q * 4 + 0]);
                acc[q * 4 + 1] = fmaf(v1.y, f1, acc[q * 4 + 1]);
                acc[q * 4 + 2] = fmaf(v1.z, f1, acc[q * 4 + 2]);
                acc[q * 4 + 3] = fmaf(v1.w, f1, acc[q * 4 + 3]);
            }
        }

        if (k < 8) {
            unsigned o[4];
            bil8(a, b, c, d, w00, w01, w10, w11, wsum, lsc, lsh, ciA, o);
            unsigned* dst = &smp[nb][pix * SSTR + cog * 4];
            dst[0] = o[0]; dst[1] = o[1]; dst[2] = o[2]; dst[3] = o[3];
            if (dual) {
                unsigned o2[4];
                bil8(a2, b2, c2, d2, w00, w01, w10, w11, wsum, lsc, lsh, 32, o2);
                unsigned* dd = &smp[nb][pix * SSTR + 16];
                dd[0] = o2[0]; dd[1] = o2[1]; dd[2] = o2[2]; dd[3] = o2[3];
            }
#pragma unroll
            for (int r = 0; r < 5; ++r) lw[nb][r * 512 + t] = wld[r];
        }
        __syncthreads();
    }

#pragma unroll
    for (int j = 0; j < 16; ++j) {
        float v = fmaxf(acc[j], 0.f);
        __builtin_nontemporal_store(v,
            &em[((size_t)(img * 64 + cog * 16 + j) << 12) + lpos]);
    }
}

// ---------------------------------------------------------------------------
// BN stats, NHWC fp32: blockDim=320, thread owns channel tid%C.
// ---------------------------------------------------------------------------
template <int C>
__global__ void bn_partial_nhwc(const float* __restrict__ src, float* __restrict__ sums) {
    const size_t total = (size_t)NPIX * C;
    size_t stride = (size_t)gridDim.x * blockDim.x;
    float s = 0.f, q = 0.f;
    for (size_t i = (size_t)blockIdx.x * blockDim.x + threadIdx.x; i < total; i += stride) {
        float v = src[i];
        s += v;
        q += v * v;
    }
    __shared__ float ls[320], lq[320];
    ls[threadIdx.x] = s;
    lq[threadIdx.x] = q;
    __syncthreads();
    if (threadIdx.x < C) {
        float a = 0.f, bb = 0.f;
        for (int j = threadIdx.x; j < 320; j += C) {
            a += ls[j];
            bb += lq[j];
        }
        atomicAdd(&sums[threadIdx.x], a);
        atomicAdd(&sums[C + threadIdx.x], bb);
    }
}

// BN stats, NHWC bf16 (dword pairs): thread owns channel-pair (tid % (C/2)).
template <int C>
__global__ void bn_partial_nhwc_bf16(const unsigned short* __restrict__ src,
                                     float* __restrict__ sums) {
    const int CP = C / 2;
    const size_t totalu = (size_t)NPIX * CP;
    const unsigned int* s32 = (const unsigned int*)src;
    size_t stride = (size_t)gridDim.x * blockDim.x;
    float s0 = 0.f, q0 = 0.f, s1 = 0.f, q1 = 0.f;
    for (size_t i = (size_t)blockIdx.x * blockDim.x + threadIdx.x; i < totalu; i += stride) {
        unsigned int u = s32[i];
        float a = bf_lo(u), b = bf_hi(u);
        s0 += a; q0 += a * a;
        s1 += b; q1 += b * b;
    }
    __shared__ float l0[320], m0[320], l1[320], m1[320];
    l0[threadIdx.x] = s0; m0[threadIdx.x] = q0;
    l1[threadIdx.x] = s1; m1[threadIdx.x] = q1;
    __syncthreads();
    if (threadIdx.x < C) {
        int cp = threadIdx.x >> 1, hi = threadIdx.x & 1;
        float a = 0.f, bb = 0.f;
        for (int j = cp; j < 320; j += CP) {
            a += hi ? l1[j] : l0[j];
            bb += hi ? m1[j] : m0[j];
        }
        atomicAdd(&sums[threadIdx.x], a);
        atomicAdd(&sums[C + threadIdx.x], bb);
    }
}

// BN stats over NCHW tensor (stage 4 / em), float4 reads.
__global__ void bn_partial_nchw(const float* __restrict__ src, int C, int parts,
                                float* __restrict__ sums) {
    int c = blockIdx.x / parts;
    int part = blockIdx.x % parts;
    int chunk = NPIX / parts;
    int start = part * chunk;
    float s = 0.f, q = 0.f;
    for (int i4 = start / 4 + threadIdx.x; i4 < (start + chunk) / 4; i4 += blockDim.x) {
        int p4 = i4 * 4;
        int bb = p4 >> 12, pos = p4 & 4095;
        float4 v = *(const float4*)&src[((size_t)(bb * C + c) << 12) + pos];
        s += v.x + v.y + v.z + v.w;
        q += v.x * v.x + v.y * v.y + v.z * v.z + v.w * v.w;
    }
    __shared__ float ls[256], lq[256];
    ls[threadIdx.x] = s;
    lq[threadIdx.x] = q;
    __syncthreads();
    for (int st = 128; st > 0; st >>= 1) {
        if (threadIdx.x < st) {
            ls[threadIdx.x] += ls[threadIdx.x + st];
            lq[threadIdx.x] += lq[threadIdx.x + st];
        }
        __syncthreads();
    }
    if (threadIdx.x == 0) {
        atomicAdd(&sums[c], ls[0]);
        atomicAdd(&sums[C + c], lq[0]);
    }
}

__global__ void bn_finalize_kernel(const float* __restrict__ sums, int C,
                                   const float* __restrict__ g,
                                   const float* __restrict__ b,
                                   float* __restrict__ scale,
                                   float* __restrict__ shift) {
    int c = threadIdx.x;
    if (c >= C) return;
    const float invN = 1.f / (float)NPIX;
    float mean = sums[c] * invN;
    float var = sums[C + c] * invN - mean * mean;
    float sc = g[c] * rsqrtf(var + 1e-5f);
    scale[c] = sc;
    shift[c] = b[c] - mean * sc;
}

// ---------------------------------------------------------------------------
// Fused stage-4 BN apply (in-place on em, NCHW) + quadrant pool.
// ---------------------------------------------------------------------------
__global__ void bn4_apply_pool(float* __restrict__ em,
                               const float* __restrict__ scale,
                               const float* __restrict__ shift,
                               float* __restrict__ pw) {
    int bc = blockIdx.x;
    int c = bc & 63;
    int t = threadIdx.x;
    float sc = scale[c], sh = shift[c];
    float* base = em + ((size_t)bc << 12);
    int pos = t * 16;
    int quad = ((pos >= 2048) ? 2 : 0) + ((pos & 63) >> 5);
    float s = 0.f;
#pragma unroll
    for (int k4 = 0; k4 < 4; ++k4) {
        float4 v = *(float4*)(base + pos + k4 * 4);
        v.x = fmaf(v.x, sc, sh);
        v.y = fmaf(v.y, sc, sh);
        v.z = fmaf(v.z, sc, sh);
        v.w = fmaf(v.w, sc, sh);
        *(float4*)(base + pos + k4 * 4) = v;
        s += v.x + v.y + v.z + v.w;
    }
    __shared__ float qs[4];
    if (t < 4) qs[t] = 0.f;
    __syncthreads();
    atomicAdd(&qs[quad], s);
    __syncthreads();
    if (t < 4) pw[bc * 4 + t] = qs[t] * (1.f / 1024.f);
}

__global__ void fc_softmax_kernel(const float* __restrict__ pw,
                                  const float* __restrict__ fw,
                                  const float* __restrict__ fb,
                                  float* __restrict__ out) {
    int b = blockIdx.x;
    int t = threadIdx.x;
    __shared__ float logits[10];
    if (t < 10) {
        float acc = fb[t];
        const float* p = pw + b * 256;
        for (int q = 0; q < 256; ++q) acc = fmaf(p[q], fw[t * 256 + q], acc);
        logits[t] = acc;
    }
    __syncthreads();
    if (t == 0) {
        float m = -1e30f;
        for (int q = 0; q < 10; ++q) m = fmaxf(m, logits[q]);
        float e[10], sum = 0.f;
        for (int q = 0; q < 10; ++q) { e[q] = expf(logits[q] - m); sum += e[q]; }
        float inv = 1.f / sum;
        for (int q = 0; q < 10; ++q) out[b * 10 + q] = e[q] * inv;
    }
}

// ---------------------------------------------------------------------------
extern "C" void kernel_launch(void* const* d_in, const int* in_sizes, int n_in,
                              void* d_out, int out_size, void* d_ws, size_t ws_size,
                              hipStream_t stream) {
    (void)in_sizes; (void)n_in; (void)out_size; (void)ws_size;

    const float* x   = (const float*)d_in[0];
    const float* w1  = (const float*)d_in[1];
    const float* g1  = (const float*)d_in[2];
    const float* b1  = (const float*)d_in[3];
    const float* w2  = (const float*)d_in[4];
    const float* bc2 = (const float*)d_in[5];
    const float* g2  = (const float*)d_in[6];
    const float* b2  = (const float*)d_in[7];
    const float* w3  = (const float*)d_in[8];
    const float* wd1 = (const float*)d_in[9];
    const float* g3  = (const float*)d_in[10];
    const float* b3  = (const float*)d_in[11];
    const float* w4  = (const float*)d_in[12];
    const float* bc4 = (const float*)d_in[13];
    const float* wd2 = (const float*)d_in[14];
    const float* g4  = (const float*)d_in[15];
    const float* b4  = (const float*)d_in[16];
    const float* fw  = (const float*)d_in[17];
    const float* fb  = (const float*)d_in[18];

    float* out = (float*)d_out;
    float* softout = out;                         // 64*10
    float* em = out + 640;                        // 64ch NCHW fp32

    float* ws = (float*)d_ws;
    float* h1 = ws;                                                  // NHWC  8ch fp32
    unsigned short* h2b = (unsigned short*)(h1 + (size_t)2097152);   // NHWC 20ch bf16
    unsigned short* h3b = h2b + (size_t)5242880;                     // NHWC 40ch bf16
    unsigned* offu = (unsigned*)(h3b + (size_t)10485760);            // fp16 pair planes
    float* sums = (float*)(offu + (size_t)9 * NPIX);                 // 128
    float* scale = sums + 128;
    float* shift = scale + 64;
    float* pw = shift + 64;

    dim3 blk(TPB);
    dim3 gpix(BATCH * PIXBLK);                    // 512

    // stage 1
    conv3x3_k<3, 8, true, false, false, true, false, 0>
        <<<gpix, blk, 0, stream>>>(x, w1, nullptr, nullptr, nullptr, h1);
    hipMemsetAsync(sums, 0, 128 * sizeof(float), stream);
    bn_partial_nhwc<8><<<256, 320, 0, stream>>>(h1, sums);
    bn_finalize_kernel<<<1, 64, 0, stream>>>(sums, 8, g1, b1, scale, shift);

    // stage 2
    conv3x3_k<8, 20, true, true, true, false, false, 1>
        <<<gpix, blk, 0, stream>>>(h1, w2, bc2, scale, shift, h2b);
    hipMemsetAsync(sums, 0, 128 * sizeof(float), stream);
    bn_partial_nhwc_bf16<20><<<256, 320, 0, stream>>>(h2b, sums);
    bn_finalize_kernel<<<1, 64, 0, stream>>>(sums, 20, g2, b2, scale, shift);

    // stage 3
    conv3x3_k<20, 18, false, false, true, false, true, 2>
        <<<gpix, blk, 0, stream>>>(h2b, w3, nullptr, scale, shift, offu);
    deform_k<20, 40, 20, 2>
        <<<dim3(BATCH * PIXBLK * 2), blk, 0, stream>>>(h2b, offu, wd1, scale, shift, h3b);
    hipMemsetAsync(sums, 0, 128 * sizeof(float), stream);
    bn_partial_nhwc_bf16<40><<<256, 320, 0, stream>>>(h3b, sums);
    bn_finalize_kernel<<<1, 64, 0, stream>>>(sums, 40, g3, b3, scale, shift);

    // stage 4: offset conv2; deform2 (LDS sample-share, sample-once)
    conv3x3_k<40, 18, false, true, true, false, true, 2>
        <<<gpix, blk, 0, stream>>>(h3b, w4, bc4, scale, shift, offu);
    deform2_smp_k<<<dim3(2048), blk, 0, stream>>>(h3b, offu, wd2, scale, shift, em);
    hipMemsetAsync(sums, 0, 128 * sizeof(float), stream);
    bn_partial_nchw<<<64 * 32, 256, 0, stream>>>(em, 64, 32, sums);
    bn_finalize_kernel<<<1, 64, 0, stream>>>(sums, 64, g4, b4, scale, shift);

    bn4_apply_pool<<<64 * 64, 256, 0, stream>>>(em, scale, shift, pw);
    fc_softmax_kernel<<<64, 64, 0, stream>>>(pw, fw, fb, softout);
}

// Round 11
// 594.250 us; speedup vs baseline: 17.3565x; 17.3565x over previous
//
#include <hip/hip_runtime.h>

#define IMW 64
#define HW 4096
#define BATCH 64
#define NPIX (BATCH * HW)   // 262144
#define TPB 512             // threads per spatial block
#define PIXBLK 8            // pixel-blocks per image (4096/512)

// ---------------- bf16 helpers (manual, RNE) ----------------
__device__ inline float bfbits(unsigned int hi16) {
    union { unsigned int i; float f; } v; v.i = hi16; return v.f;
}
__device__ inline float bf_lo(unsigned int u) { return bfbits(u << 16); }
__device__ inline float bf_hi(unsigned int u) { return bfbits(u & 0xffff0000u); }
__device__ inline unsigned short f2bf(float f) {
    union { float f; unsigned int i; } v; v.f = f;
    unsigned int i = v.i;
    i += 0x7fff + ((i >> 16) & 1);
    return (unsigned short)(i >> 16);
}

// ---------------- fp16 pair helpers ----------------
__device__ inline unsigned pack_h2(float a, float b) {
    union { unsigned u; _Float16 h[2]; } v;
    v.h[0] = (_Float16)a;
    v.h[1] = (_Float16)b;
    return v.u;
}
__device__ inline float h_lo(unsigned u) {
    union { unsigned u; _Float16 h[2]; } v; v.u = u; return (float)v.h[0];
}
__device__ inline float h_hi(unsigned u) {
    union { unsigned u; _Float16 h[2]; } v; v.u = u; return (float)v.h[1];
}

// ---------------------------------------------------------------------------
// XCD-pinned swizzle (verified R3: FETCH 2.4GB -> 455MB). XCD = lin & 7 owns
// images [8*xcd, 8*xcd+8); all pixel/co blocks of an image on one XCD.
// ---------------------------------------------------------------------------
template <int CO_BLOCKS>
__device__ inline void swz(int lin, int& img, int& xblk, int& cob) {
    const int per_img = PIXBLK * CO_BLOCKS;
    int xcd = lin & 7;
    int s = lin >> 3;
    img = xcd * 8 + s / per_img;
    int r = s % per_img;
    cob = r / PIXBLK;
    xblk = r % PIXBLK;
}

// ---------------------------------------------------------------------------
// Direct 3x3 conv, pad=1. NHWC activations (stage-1 input NCHW fp32).
// IN_BF16: bf16 NHWC input. OUT_MODE: 0 = fp32 NHWC, 1 = bf16 NHWC packed,
// 2 = fp16 dword-planes [tap][pixel] (for offsets, COUT=18 -> 9 planes).
// Weights in LDS [k][ci][co], dest-linear staging (no bank conflicts).
// R5/R8/R9/R10 LESSON: at TPB=512 the allocator pins these bodies to 64
// arch-VGPRs; any live set beyond ~60 regs spills to scratch (WRITE_SIZE
// blowup). Keep per-thread state small; no launch_bounds min-waves.
// ---------------------------------------------------------------------------
template <int CIN, int COUT, bool RELU, bool BIAS, bool AFF, bool IN_NCHW,
          bool IN_BF16, int OUT_MODE>
__global__ void conv3x3_k(const void* __restrict__ in_,
                          const float* __restrict__ w,
                          const float* __restrict__ bias,
                          const float* __restrict__ iscale,
                          const float* __restrict__ ishift,
                          void* __restrict__ out_) {
    __shared__ float lw[9 * CIN * COUT];
    __shared__ float lb[COUT];
    __shared__ float lsc[CIN];
    __shared__ float lsh[CIN];

    for (int dst = threadIdx.x; dst < 9 * CIN * COUT; dst += blockDim.x) {
        int co = dst % COUT;
        int kci = dst / COUT;
        int k = kci / CIN;
        int ci = kci % CIN;
        lw[dst] = w[(size_t)co * (CIN * 9) + ci * 9 + k];
    }
    if (threadIdx.x < COUT) lb[threadIdx.x] = BIAS ? bias[threadIdx.x] : 0.f;
    if (AFF && threadIdx.x < CIN) {
        lsc[threadIdx.x] = iscale[threadIdx.x];
        lsh[threadIdx.x] = ishift[threadIdx.x];
    }
    __syncthreads();

    int img, xblk, cob;
    swz<1>(blockIdx.x, img, xblk, cob);
    int b = img;
    int pos = xblk * TPB + threadIdx.x;
    int p = (b << 12) + pos;
    int y = pos >> 6;
    int x = pos & 63;

    float acc[COUT];
#pragma unroll
    for (int co = 0; co < COUT; ++co) acc[co] = lb[co];

#pragma unroll 1
    for (int k = 0; k < 9; ++k) {
        int ky = k / 3, kx = k - ky * 3;
        int yy = y + ky - 1, xx = x + kx - 1;
        if (yy < 0 || yy >= IMW || xx < 0 || xx >= IMW) continue;

        float vin[CIN];
        if constexpr (IN_NCHW) {
            const float* ip = (const float*)in_;
#pragma unroll
            for (int ci = 0; ci < CIN; ++ci)
                vin[ci] = ip[((size_t)(b * CIN + ci) << 12) + yy * IMW + xx];
        } else if constexpr (!IN_BF16) {
            const float* ip = (const float*)in_ + ((size_t)((b << 12) + yy * IMW + xx)) * CIN;
#pragma unroll
            for (int c4 = 0; c4 < CIN / 4; ++c4) {
                float4 v = *(const float4*)(ip + c4 * 4);
                vin[c4 * 4 + 0] = v.x;
                vin[c4 * 4 + 1] = v.y;
                vin[c4 * 4 + 2] = v.z;
                vin[c4 * 4 + 3] = v.w;
            }
        } else if constexpr (CIN % 8 == 0) {
            const uint4* ip = (const uint4*)((const unsigned short*)in_ +
                                             ((size_t)((b << 12) + yy * IMW + xx)) * CIN);
#pragma unroll
            for (int c8 = 0; c8 < CIN / 8; ++c8) {
                uint4 u = ip[c8];
                vin[c8 * 8 + 0] = bf_lo(u.x); vin[c8 * 8 + 1] = bf_hi(u.x);
                vin[c8 * 8 + 2] = bf_lo(u.y); vin[c8 * 8 + 3] = bf_hi(u.y);
                vin[c8 * 8 + 4] = bf_lo(u.z); vin[c8 * 8 + 5] = bf_hi(u.z);
                vin[c8 * 8 + 6] = bf_lo(u.w); vin[c8 * 8 + 7] = bf_hi(u.w);
            }
        } else {
            const uint2* ip = (const uint2*)((const unsigned short*)in_ +
                                             ((size_t)((b << 12) + yy * IMW + xx)) * CIN);
#pragma unroll
            for (int c4 = 0; c4 < CIN / 4; ++c4) {
                uint2 u = ip[c4];
                vin[c4 * 4 + 0] = bf_lo(u.x); vin[c4 * 4 + 1] = bf_hi(u.x);
                vin[c4 * 4 + 2] = bf_lo(u.y); vin[c4 * 4 + 3] = bf_hi(u.y);
            }
        }
        if constexpr (AFF) {
#pragma unroll
            for (int ci = 0; ci < CIN; ++ci)
                vin[ci] = fmaf(vin[ci], lsc[ci], lsh[ci]);
        }
#pragma unroll
        for (int ci = 0; ci < CIN; ++ci) {
            float s = vin[ci];
            const float* wr = &lw[(k * CIN + ci) * COUT];
#pragma unroll
            for (int co = 0; co < COUT; ++co)
                acc[co] = fmaf(wr[co], s, acc[co]);
        }
    }

    if (RELU) {
#pragma unroll
        for (int co = 0; co < COUT; ++co) acc[co] = fmaxf(acc[co], 0.f);
    }

    if constexpr (OUT_MODE == 2) {
        // fp16 pair planes: plane j holds channels (2j, 2j+1) at [j*NPIX + p]
        unsigned* o = (unsigned*)out_;
#pragma unroll
        for (int i = 0; i < COUT / 2; ++i)
            o[(size_t)i * NPIX + p] = pack_h2(acc[2 * i], acc[2 * i + 1]);
    } else if constexpr (OUT_MODE == 1) {
        unsigned int us[COUT / 2];
#pragma unroll
        for (int i = 0; i < COUT / 2; ++i)
            us[i] = (unsigned int)f2bf(acc[2 * i]) | ((unsigned int)f2bf(acc[2 * i + 1]) << 16);
        uint2* o2 = (uint2*)((unsigned short*)out_ + (size_t)p * COUT);
#pragma unroll
        for (int i = 0; i < COUT / 4; ++i)
            o2[i] = make_uint2(us[2 * i], us[2 * i + 1]);
    } else {
        float* op = (float*)out_ + (size_t)p * COUT;
        if constexpr (COUT % 4 == 0) {
#pragma unroll
            for (int c4 = 0; c4 < COUT / 4; ++c4)
                *(float4*)(op + c4 * 4) =
                    make_float4(acc[c4 * 4], acc[c4 * 4 + 1], acc[c4 * 4 + 2], acc[c4 * 4 + 3]);
        } else {
#pragma unroll
            for (int c2 = 0; c2 < COUT / 2; ++c2)
                *(float2*)(op + c2 * 2) = make_float2(acc[c2 * 2], acc[c2 * 2 + 1]);
        }
    }
}

// ---------------------------------------------------------------------------
// Deformable conv 3x3, bf16 NHWC input + fp16 plane offsets (hoisted loads).
// BN affine fused via wsum trick. OUT_NCHW: fp32 nontemporal (em);
// else bf16 NHWC packed (h3).
// PERTAP: double-buffered per-tap weight staging (2*CIN*COUT_BLK floats LDS)
// -> 4 blocks/CU resident (32-wave cap). R7-proven config: deform2 uses
// COUT_BLK=32 / CO_BLOCKS=2 (acc[32] fits the 64-VGPR wall; COUT_BLK=64
// spills — R8/R9). Requires COUT_BLK power-of-2, TPB % COUT_BLK == 0.
// ---------------------------------------------------------------------------
template <int CIN, int COUT_TOT, int COUT_BLK, int CO_BLOCKS, bool OUT_NCHW, bool PERTAP>
__global__ void deform_k(const void* __restrict__ in_,
                         const unsigned* __restrict__ off,   // fp16 pair planes
                         const float* __restrict__ w,
                         const float* __restrict__ iscale,
                         const float* __restrict__ ishift,
                         void* __restrict__ out_) {
    constexpr int WSLICE = CIN * COUT_BLK;          // weights per tap
    constexpr int LWSZ = PERTAP ? 2 * WSLICE : 9 * WSLICE;
    __shared__ float lw[LWSZ];
    __shared__ float lsc[CIN];
    __shared__ float lsh[CIN];

    int img, xblk, cob;
    swz<CO_BLOCKS>(blockIdx.x, img, xblk, cob);
    int co_base = cob * COUT_BLK;

    if (threadIdx.x < CIN) {
        lsc[threadIdx.x] = iscale[threadIdx.x];
        lsh[threadIdx.x] = ishift[threadIdx.x];
    }

    // per-thread weight-source pointer: co fixed, ci advances by TPB/COUT_BLK per j
    const float* wsrc = nullptr;
    if constexpr (PERTAP) {
        wsrc = w + (size_t)(co_base + (threadIdx.x & (COUT_BLK - 1))) * (CIN * 9) +
               (threadIdx.x / COUT_BLK) * 9;
    } else {
        for (int dst = threadIdx.x; dst < 9 * WSLICE; dst += blockDim.x) {
            int co = dst % COUT_BLK;
            int kci = dst / COUT_BLK;
            int k = kci / CIN;
            int ci = kci % CIN;
            lw[dst] = w[(size_t)(co_base + co) * (CIN * 9) + ci * 9 + k];
        }
    }

    constexpr int NFULL = WSLICE / TPB;             // full rounds of TPB
    constexpr int REM = WSLICE - NFULL * TPB;       // remainder threads
    constexpr int CISTEP = TPB / COUT_BLK;          // ci advance per round

    auto stage_tap = [&](int k, int buf) {
        if constexpr (PERTAP) {
            const float* src = wsrc + k;
            float* d = lw + buf * WSLICE + threadIdx.x;
#pragma unroll
            for (int j = 0; j < NFULL; ++j)
                d[j * TPB] = src[(size_t)j * CISTEP * 9];
            if (REM > 0 && threadIdx.x < REM)
                d[NFULL * TPB] = src[(size_t)NFULL * CISTEP * 9];
        }
    };

    if constexpr (PERTAP) stage_tap(0, 0);
    __syncthreads();

    int b = img;
    int pos = xblk * TPB + threadIdx.x;
    int p = (b << 12) + pos;
    int y = pos >> 6;
    int x = pos & 63;

    float acc[COUT_BLK];
#pragma unroll
    for (int co = 0; co < COUT_BLK; ++co) acc[co] = 0.f;

    // hoist all 9 tap offsets (independent coalesced dword loads)
    unsigned od[9];
#pragma unroll
    for (int j = 0; j < 9; ++j) od[j] = off[(size_t)j * NPIX + p];

    const unsigned short* ib = (const unsigned short*)in_ + (size_t)b * HW * CIN;

#pragma unroll 1
    for (int k = 0; k < 9; ++k) {
        if constexpr (PERTAP) {
            if (k < 8) stage_tap(k + 1, (k + 1) & 1);
        }
        const int kbase = PERTAP ? (k & 1) * CIN : k * CIN;

        int ky = k / 3, kx = k - ky * 3;
        float py = (float)(y + ky - 1) + h_lo(od[k]);
        float px = (float)(x + kx - 1) + h_hi(od[k]);
        float fy = floorf(py), fx = floorf(px);
        float wy = py - fy, wx = px - fx;
        int y0 = (int)fy, x0 = (int)fx;
        int y1 = y0 + 1, x1 = x0 + 1;
        bool vy0 = (unsigned)y0 < (unsigned)IMW;
        bool vy1 = (unsigned)y1 < (unsigned)IMW;
        bool vx0 = (unsigned)x0 < (unsigned)IMW;
        bool vx1 = (unsigned)x1 < (unsigned)IMW;
        int cy0 = min(max(y0, 0), IMW - 1), cy1 = min(max(y1, 0), IMW - 1);
        int cx0 = min(max(x0, 0), IMW - 1), cx1 = min(max(x1, 0), IMW - 1);
        float w00 = (1.f - wy) * (1.f - wx) * ((vy0 & vx0) ? 1.f : 0.f);
        float w01 = (1.f - wy) * wx * ((vy0 & vx1) ? 1.f : 0.f);
        float w10 = wy * (1.f - wx) * ((vy1 & vx0) ? 1.f : 0.f);
        float w11 = wy * wx * ((vy1 & vx1) ? 1.f : 0.f);
        float wsum = w00 + w01 + w10 + w11;

        if constexpr (CIN % 8 == 0) {
            const uint4* q00 = (const uint4*)(ib + (size_t)(cy0 * IMW + cx0) * CIN);
            const uint4* q01 = (const uint4*)(ib + (size_t)(cy0 * IMW + cx1) * CIN);
            const uint4* q10 = (const uint4*)(ib + (size_t)(cy1 * IMW + cx0) * CIN);
            const uint4* q11 = (const uint4*)(ib + (size_t)(cy1 * IMW + cx1) * CIN);
#pragma unroll 1
            for (int c8 = 0; c8 < CIN / 8; ++c8) {
                uint4 a = q00[c8], bq = q01[c8], c = q10[c8], d = q11[c8];
#pragma unroll
                for (int h = 0; h < 4; ++h) {
                    unsigned int ua = (&a.x)[h], ub = (&bq.x)[h];
                    unsigned int uc = (&c.x)[h], ud = (&d.x)[h];
                    int ci0 = c8 * 8 + h * 2;
                    float r0 = w00 * bf_lo(ua) + w01 * bf_lo(ub) +
                               w10 * bf_lo(uc) + w11 * bf_lo(ud);
                    float r1 = w00 * bf_hi(ua) + w01 * bf_hi(ub) +
                               w10 * bf_hi(uc) + w11 * bf_hi(ud);
                    float s0 = fmaf(r0, lsc[ci0], lsh[ci0] * wsum);
                    float s1 = fmaf(r1, lsc[ci0 + 1], lsh[ci0 + 1] * wsum);
                    const float* wr0 = &lw[(kbase + ci0) * COUT_BLK];
                    const float* wr1 = &lw[(kbase + ci0 + 1) * COUT_BLK];
#pragma unroll
                    for (int co = 0; co < COUT_BLK; ++co)
                        acc[co] = fmaf(wr0[co], s0, acc[co]);
#pragma unroll
                    for (int co = 0; co < COUT_BLK; ++co)
                        acc[co] = fmaf(wr1[co], s1, acc[co]);
                }
            }
        } else {
            const uint2* q00 = (const uint2*)(ib + (size_t)(cy0 * IMW + cx0) * CIN);
            const uint2* q01 = (const uint2*)(ib + (size_t)(cy0 * IMW + cx1) * CIN);
            const uint2* q10 = (const uint2*)(ib + (size_t)(cy1 * IMW + cx0) * CIN);
            const uint2* q11 = (const uint2*)(ib + (size_t)(cy1 * IMW + cx1) * CIN);
#pragma unroll
            for (int c4 = 0; c4 < CIN / 4; ++c4) {
                uint2 a = q00[c4], bq = q01[c4], c = q10[c4], d = q11[c4];
#pragma unroll
                for (int h = 0; h < 2; ++h) {
                    unsigned int ua = (&a.x)[h], ub = (&bq.x)[h];
                    unsigned int uc = (&c.x)[h], ud = (&d.x)[h];
                    int ci0 = c4 * 4 + h * 2;
                    float r0 = w00 * bf_lo(ua) + w01 * bf_lo(ub) +
                               w10 * bf_lo(uc) + w11 * bf_lo(ud);
                    float r1 = w00 * bf_hi(ua) + w01 * bf_hi(ub) +
                               w10 * bf_hi(uc) + w11 * bf_hi(ud);
                    float s0 = fmaf(r0, lsc[ci0], lsh[ci0] * wsum);
                    float s1 = fmaf(r1, lsc[ci0 + 1], lsh[ci0 + 1] * wsum);
                    const float* wr0 = &lw[(kbase + ci0) * COUT_BLK];
                    const float* wr1 = &lw[(kbase + ci0 + 1) * COUT_BLK];
#pragma unroll
                    for (int co = 0; co < COUT_BLK; ++co)
                        acc[co] = fmaf(wr0[co], s0, acc[co]);
#pragma unroll
                    for (int co = 0; co < COUT_BLK; ++co)
                        acc[co] = fmaf(wr1[co], s1, acc[co]);
                }
            }
        }

        if constexpr (PERTAP) __syncthreads();
    }

#pragma unroll
    for (int co = 0; co < COUT_BLK; ++co) acc[co] = fmaxf(acc[co], 0.f);

    if constexpr (OUT_NCHW) {
        float* o = (float*)out_;
#pragma unroll
        for (int co = 0; co < COUT_BLK; ++co)
            __builtin_nontemporal_store(acc[co],
                &o[((size_t)(b * COUT_TOT + co_base + co) << 12) + pos]);
    } else {
        unsigned int us[COUT_BLK / 2];
#pragma unroll
        for (int i = 0; i < COUT_BLK / 2; ++i)
            us[i] = (unsigned int)f2bf(acc[2 * i]) | ((unsigned int)f2bf(acc[2 * i + 1]) << 16);
        unsigned short* ob = (unsigned short*)out_ + (size_t)p * COUT_TOT + co_base;
        if constexpr (COUT_BLK % 8 == 0) {
            uint4* o4 = (uint4*)ob;
#pragma unroll
            for (int i = 0; i < COUT_BLK / 8; ++i)
                o4[i] = make_uint4(us[4 * i], us[4 * i + 1], us[4 * i + 2], us[4 * i + 3]);
        } else {
            uint2* o2 = (uint2*)ob;
#pragma unroll
            for (int i = 0; i < COUT_BLK / 4; ++i)
                o2[i] = make_uint2(us[2 * i], us[2 * i + 1]);
        }
    }
}

// ---------------------------------------------------------------------------
// BN stats, NHWC fp32: blockDim=320, thread owns channel tid%C.
// ---------------------------------------------------------------------------
template <int C>
__global__ void bn_partial_nhwc(const float* __restrict__ src, float* __restrict__ sums) {
    const size_t total = (size_t)NPIX * C;
    size_t stride = (size_t)gridDim.x * blockDim.x;
    float s = 0.f, q = 0.f;
    for (size_t i = (size_t)blockIdx.x * blockDim.x + threadIdx.x; i < total; i += stride) {
        float v = src[i];
        s += v;
        q += v * v;
    }
    __shared__ float ls[320], lq[320];
    ls[threadIdx.x] = s;
    lq[threadIdx.x] = q;
    __syncthreads();
    if (threadIdx.x < C) {
        float a = 0.f, bb = 0.f;
        for (int j = threadIdx.x; j < 320; j += C) {
            a += ls[j];
            bb += lq[j];
        }
        atomicAdd(&sums[threadIdx.x], a);
        atomicAdd(&sums[C + threadIdx.x], bb);
    }
}

// BN stats, NHWC bf16 (dword pairs): thread owns channel-pair (tid % (C/2)).
template <int C>
__global__ void bn_partial_nhwc_bf16(const unsigned short* __restrict__ src,
                                     float* __restrict__ sums) {
    const int CP = C / 2;
    const size_t totalu = (size_t)NPIX * CP;
    const unsigned int* s32 = (const unsigned int*)src;
    size_t stride = (size_t)gridDim.x * blockDim.x;   // 256*320 = 81920, % CP == 0
    float s0 = 0.f, q0 = 0.f, s1 = 0.f, q1 = 0.f;
    for (size_t i = (size_t)blockIdx.x * blockDim.x + threadIdx.x; i < totalu; i += stride) {
        unsigned int u = s32[i];
        float a = bf_lo(u), b = bf_hi(u);
        s0 += a; q0 += a * a;
        s1 += b; q1 += b * b;
    }
    __shared__ float l0[320], m0[320], l1[320], m1[320];
    l0[threadIdx.x] = s0; m0[threadIdx.x] = q0;
    l1[threadIdx.x] = s1; m1[threadIdx.x] = q1;
    __syncthreads();
    if (threadIdx.x < C) {
        int cp = threadIdx.x >> 1, hi = threadIdx.x & 1;
        float a = 0.f, bb = 0.f;
        for (int j = cp; j < 320; j += CP) {
            a += hi ? l1[j] : l0[j];
            bb += hi ? m1[j] : m0[j];
        }
        atomicAdd(&sums[threadIdx.x], a);
        atomicAdd(&sums[C + threadIdx.x], bb);
    }
}

// BN stats over NCHW tensor (stage 4 / em), float4 reads.
__global__ void bn_partial_nchw(const float* __restrict__ src, int C, int parts,
                                float* __restrict__ sums) {
    int c = blockIdx.x / parts;
    int part = blockIdx.x % parts;
    int chunk = NPIX / parts;                 // multiple of 4096
    int start = part * chunk;
    float s = 0.f, q = 0.f;
    for (int i4 = start / 4 + threadIdx.x; i4 < (start + chunk) / 4; i4 += blockDim.x) {
        int p4 = i4 * 4;
        int bb = p4 >> 12, pos = p4 & 4095;
        float4 v = *(const float4*)&src[((size_t)(bb * C + c) << 12) + pos];
        s += v.x + v.y + v.z + v.w;
        q += v.x * v.x + v.y * v.y + v.z * v.z + v.w * v.w;
    }
    __shared__ float ls[256], lq[256];
    ls[threadIdx.x] = s;
    lq[threadIdx.x] = q;
    __syncthreads();
    for (int st = 128; st > 0; st >>= 1) {
        if (threadIdx.x < st) {
            ls[threadIdx.x] += ls[threadIdx.x + st];
            lq[threadIdx.x] += lq[threadIdx.x + st];
        }
        __syncthreads();
    }
    if (threadIdx.x == 0) {
        atomicAdd(&sums[c], ls[0]);
        atomicAdd(&sums[C + c], lq[0]);
    }
}

__global__ void bn_finalize_kernel(const float* __restrict__ sums, int C,
                                   const float* __restrict__ g,
                                   const float* __restrict__ b,
                                   float* __restrict__ scale,
                                   float* __restrict__ shift) {
    int c = threadIdx.x;
    if (c >= C) return;
    const float invN = 1.f / (float)NPIX;
    float mean = sums[c] * invN;
    float var = sums[C + c] * invN - mean * mean;
    float sc = g[c] * rsqrtf(var + 1e-5f);
    scale[c] = sc;
    shift[c] = b[c] - mean * sc;
}

// ---------------------------------------------------------------------------
// Fused stage-4 BN apply (in-place on em, NCHW) + quadrant pool.
// ---------------------------------------------------------------------------
__global__ void bn4_apply_pool(float* __restrict__ em,
                               const float* __restrict__ scale,
                               const float* __restrict__ shift,
                               float* __restrict__ pw) {
    int bc = blockIdx.x;
    int c = bc & 63;
    int t = threadIdx.x;
    float sc = scale[c], sh = shift[c];
    float* base = em + ((size_t)bc << 12);
    int pos = t * 16;
    int quad = ((pos >= 2048) ? 2 : 0) + ((pos & 63) >> 5);
    float s = 0.f;
#pragma unroll
    for (int k4 = 0; k4 < 4; ++k4) {
        float4 v = *(float4*)(base + pos + k4 * 4);
        v.x = fmaf(v.x, sc, sh);
        v.y = fmaf(v.y, sc, sh);
        v.z = fmaf(v.z, sc, sh);
        v.w = fmaf(v.w, sc, sh);
        *(float4*)(base + pos + k4 * 4) = v;
        s += v.x + v.y + v.z + v.w;
    }
    __shared__ float qs[4];
    if (t < 4) qs[t] = 0.f;
    __syncthreads();
    atomicAdd(&qs[quad], s);
    __syncthreads();
    if (t < 4) pw[bc * 4 + t] = qs[t] * (1.f / 1024.f);
}

__global__ void fc_softmax_kernel(const float* __restrict__ pw,
                                  const float* __restrict__ fw,
                                  const float* __restrict__ fb,
                                  float* __restrict__ out) {
    int b = blockIdx.x;
    int t = threadIdx.x;
    __shared__ float logits[10];
    if (t < 10) {
        float acc = fb[t];
        const float* p = pw + b * 256;
        for (int q = 0; q < 256; ++q) acc = fmaf(p[q], fw[t * 256 + q], acc);
        logits[t] = acc;
    }
    __syncthreads();
    if (t == 0) {
        float m = -1e30f;
        for (int q = 0; q < 10; ++q) m = fmaxf(m, logits[q]);
        float e[10], sum = 0.f;
        for (int q = 0; q < 10; ++q) { e[q] = expf(logits[q] - m); sum += e[q]; }
        float inv = 1.f / sum;
        for (int q = 0; q < 10; ++q) out[b * 10 + q] = e[q] * inv;
    }
}

// ---------------------------------------------------------------------------
extern "C" void kernel_launch(void* const* d_in, const int* in_sizes, int n_in,
                              void* d_out, int out_size, void* d_ws, size_t ws_size,
                              hipStream_t stream) {
    (void)in_sizes; (void)n_in; (void)out_size; (void)ws_size;

    const float* x   = (const float*)d_in[0];
    const float* w1  = (const float*)d_in[1];
    const float* g1  = (const float*)d_in[2];
    const float* b1  = (const float*)d_in[3];
    const float* w2  = (const float*)d_in[4];
    const float* bc2 = (const float*)d_in[5];
    const float* g2  = (const float*)d_in[6];
    const float* b2  = (const float*)d_in[7];
    const float* w3  = (const float*)d_in[8];
    const float* wd1 = (const float*)d_in[9];
    const float* g3  = (const float*)d_in[10];
    const float* b3  = (const float*)d_in[11];
    const float* w4  = (const float*)d_in[12];
    const float* bc4 = (const float*)d_in[13];
    const float* wd2 = (const float*)d_in[14];
    const float* g4  = (const float*)d_in[15];
    const float* b4  = (const float*)d_in[16];
    const float* fw  = (const float*)d_in[17];
    const float* fb  = (const float*)d_in[18];

    float* out = (float*)d_out;
    float* softout = out;                         // 64*10
    float* em = out + 640;                        // 64ch NCHW fp32

    float* ws = (float*)d_ws;
    float* h1 = ws;                                                  // NHWC  8ch fp32: 2,097,152 floats
    unsigned short* h2b = (unsigned short*)(h1 + (size_t)2097152);   // NHWC 20ch bf16: 5,242,880 shorts
    unsigned short* h3b = h2b + (size_t)5242880;                     // NHWC 40ch bf16: 10,485,760 shorts
    unsigned* offu = (unsigned*)(h3b + (size_t)10485760);            // fp16 pair planes: 9*NPIX uints
    float* sums1 = (float*)(offu + (size_t)9 * NPIX);                // 4 stages' sums: 4*128
    float* sums2 = sums1 + 128;
    float* sums3 = sums2 + 128;
    float* sums4 = sums3 + 128;
    float* scale = sums4 + 128;                   // 64
    float* shift = scale + 64;                    // 64
    float* pw = shift + 64;                       // 64*256

    dim3 blk(TPB);
    dim3 gpix(BATCH * PIXBLK);                    // 512

    // zero all four sums regions once (one dispatch instead of four)
    hipMemsetAsync(sums1, 0, 4 * 128 * sizeof(float), stream);

    // stage 1: conv1 (NCHW fp32 in -> NHWC fp32) + relu; bn1 stats
    conv3x3_k<3, 8, true, false, false, true, false, 0>
        <<<gpix, blk, 0, stream>>>(x, w1, nullptr, nullptr, nullptr, h1);
    bn_partial_nhwc<8><<<256, 320, 0, stream>>>(h1, sums1);
    bn_finalize_kernel<<<1, 64, 0, stream>>>(sums1, 8, g1, b1, scale, shift);

    // stage 2: conv2 (+bias, affine1 fused) + relu -> h2 bf16; bn2 stats
    conv3x3_k<8, 20, true, true, true, false, false, 1>
        <<<gpix, blk, 0, stream>>>(h1, w2, bc2, scale, shift, h2b);
    bn_partial_nhwc_bf16<20><<<256, 320, 0, stream>>>(h2b, sums2);
    bn_finalize_kernel<<<1, 64, 0, stream>>>(sums2, 20, g2, b2, scale, shift);

    // stage 3: offset conv (affine2 fused, bf16 in) -> fp16 planes;
    //          deform1 (affine2 fused, 2 co-blocks, full 9-tap LDS weights)
    conv3x3_k<20, 18, false, false, true, false, true, 2>
        <<<gpix, blk, 0, stream>>>(h2b, w3, nullptr, scale, shift, offu);
    deform_k<20, 40, 20, 2, false, false>
        <<<dim3(BATCH * PIXBLK * 2), blk, 0, stream>>>(h2b, offu, wd1, scale, shift, h3b);
    bn_partial_nhwc_bf16<40><<<256, 320, 0, stream>>>(h3b, sums3);
    bn_finalize_kernel<<<1, 64, 0, stream>>>(sums3, 40, g3, b3, scale, shift);

    // stage 4: offset conv2 (+bias, affine3 fused, bf16 in) -> fp16 planes;
    //          deform2 (R7-proven: per-tap staged weights, COUT_BLK=32 x 2)
    conv3x3_k<40, 18, false, true, true, false, true, 2>
        <<<gpix, blk, 0, stream>>>(h3b, w4, bc4, scale, shift, offu);
    deform_k<40, 64, 32, 2, true, true>
        <<<dim3(BATCH * PIXBLK * 2), blk, 0, stream>>>(h3b, offu, wd2, scale, shift, em);
    bn_partial_nchw<<<64 * 32, 256, 0, stream>>>(em, 64, 32, sums4);
    bn_finalize_kernel<<<1, 64, 0, stream>>>(sums4, 64, g4, b4, scale, shift);

    // fused bn4 apply + quadrant pool; then FC + softmax
    bn4_apply_pool<<<64 * 64, 256, 0, stream>>>(em, scale, shift, pw);
    fc_softmax_kernel<<<64, 64, 0, stream>>>(pw, fw, fb, softout);
}